// Round 1
// baseline (216.011 us; speedup 1.0000x reference)
//
#include <hip/hip_runtime.h>

// GatedBlock: N=65536 rows, FEAT=2560 in-cols, OUT=2112 out-cols (f32).
// pieces: [0,256) silu | [256,1024) l=1 gate j/3 | [1024,1664) l=2 gate j/5 |
//         [1664,2112) l=3 gate j/7 ; gates live at in cols [2112,2560).
constexpr int FEAT     = 2560;
constexpr int OUT_COLS = 2112;
constexpr int GATE_OFF = 2112;
constexpr int NVEC     = 528;   // OUT_COLS / 4

__device__ __forceinline__ float sigmoidf(float x) {
    return 1.0f / (1.0f + __expf(-x));
}

__global__ __launch_bounds__(256) void gated_kernel(const float* __restrict__ in,
                                                    float* __restrict__ out) {
    const int row = blockIdx.x;
    const float* __restrict__ rin  = in  + (size_t)row * FEAT;
    const float* __restrict__ g    = rin + GATE_OFF;
    float* __restrict__       rout = out + (size_t)row * OUT_COLS;

    // 528 vec4 per row, 256 threads -> 2 full sweeps + 16-thread tail.
    for (int t = threadIdx.x; t < NVEC; t += 256) {
        float4 o;
        if (t < 64) {
            // silu piece: cols [0,256)
            const float4 v = *(const float4*)(rin + t * 4);
            o.x = v.x * sigmoidf(v.x);
            o.y = v.y * sigmoidf(v.y);
            o.z = v.z * sigmoidf(v.z);
            o.w = v.w * sigmoidf(v.w);
        } else if (t < 256) {
            // l=1: cols [256,1024), gate idx j/3
            const int j = (t - 64) * 4;
            const float4 v = *(const float4*)(rin + 256 + j);
            o.x = v.x * sigmoidf(g[(j + 0) / 3]);
            o.y = v.y * sigmoidf(g[(j + 1) / 3]);
            o.z = v.z * sigmoidf(g[(j + 2) / 3]);
            o.w = v.w * sigmoidf(g[(j + 3) / 3]);
        } else if (t < 416) {
            // l=2: cols [1024,1664), gate idx 256 + j/5
            const int j = (t - 256) * 4;
            const float4 v = *(const float4*)(rin + 1024 + j);
            o.x = v.x * sigmoidf(g[256 + (j + 0) / 5]);
            o.y = v.y * sigmoidf(g[256 + (j + 1) / 5]);
            o.z = v.z * sigmoidf(g[256 + (j + 2) / 5]);
            o.w = v.w * sigmoidf(g[256 + (j + 3) / 5]);
        } else {
            // l=3: cols [1664,2112), gate idx 384 + j/7
            const int j = (t - 416) * 4;
            const float4 v = *(const float4*)(rin + 1664 + j);
            o.x = v.x * sigmoidf(g[384 + (j + 0) / 7]);
            o.y = v.y * sigmoidf(g[384 + (j + 1) / 7]);
            o.z = v.z * sigmoidf(g[384 + (j + 2) / 7]);
            o.w = v.w * sigmoidf(g[384 + (j + 3) / 7]);
        }
        *(float4*)(rout + t * 4) = o;
    }
}

extern "C" void kernel_launch(void* const* d_in, const int* in_sizes, int n_in,
                              void* d_out, int out_size, void* d_ws, size_t ws_size,
                              hipStream_t stream) {
    const float* in = (const float*)d_in[0];
    float* out = (float*)d_out;
    const int n_rows = in_sizes[0] / FEAT;   // 65536
    gated_kernel<<<n_rows, 256, 0, stream>>>(in, out);
}

// Round 3
// 184.773 us; speedup vs baseline: 1.1691x; 1.1691x over previous
//
#include <hip/hip_runtime.h>

// GatedBlock: N=65536 rows, FEAT=2560 in-cols, OUT=2112 out-cols (f32).
// pieces: [0,256) silu | [256,1024) l=1 gate j/3 | [1024,1664) l=2 gate j/5 |
//         [1664,2112) l=3 gate j/7 ; gates live at in cols [2112,2560).
//
// R3: R2 with native ext_vector_type for the nontemporal builtins
//     (HIP float4 is a class -> rejected by __builtin_nontemporal_*).
constexpr int FEAT     = 2560;
constexpr int OUT_COLS = 2112;
constexpr int GATE_OFF = 2112;
constexpr int NGATES   = 448;
constexpr int NVEC     = 528;   // OUT_COLS / 4

typedef float f32x4 __attribute__((ext_vector_type(4)));

__device__ __forceinline__ float sigmoidf(float x) {
    return 1.0f / (1.0f + __expf(-x));
}

__global__ __launch_bounds__(256) void gated_kernel(const float* __restrict__ in,
                                                    float* __restrict__ out) {
    __shared__ float sg[NGATES];
    const int row = blockIdx.x;
    const float* __restrict__ rin  = in  + (size_t)row * FEAT;
    float* __restrict__       rout = out + (size_t)row * OUT_COLS;
    const int tid = threadIdx.x;

    // Stage sigmoid(gates): 448 floats via 224 coalesced float2 loads.
    if (tid < NGATES / 2) {
        const float2 gv = *(const float2*)(rin + GATE_OFF + tid * 2);
        sg[tid * 2 + 0] = sigmoidf(gv.x);
        sg[tid * 2 + 1] = sigmoidf(gv.y);
    }
    __syncthreads();

    // 528 vec4 per row, 256 threads -> 2 full sweeps + 16-thread tail.
    for (int t = tid; t < NVEC; t += 256) {
        f32x4 o;
        if (t < 64) {
            // silu piece: cols [0,256)
            const f32x4 v = __builtin_nontemporal_load((const f32x4*)rin + t);
            o.x = v.x * sigmoidf(v.x);
            o.y = v.y * sigmoidf(v.y);
            o.z = v.z * sigmoidf(v.z);
            o.w = v.w * sigmoidf(v.w);
        } else if (t < 256) {
            // l=1: cols [256,1024), gate idx j/3
            const int j = (t - 64) * 4;
            const f32x4 v = __builtin_nontemporal_load((const f32x4*)(rin + 256) + (t - 64));
            o.x = v.x * sg[(j + 0) / 3];
            o.y = v.y * sg[(j + 1) / 3];
            o.z = v.z * sg[(j + 2) / 3];
            o.w = v.w * sg[(j + 3) / 3];
        } else if (t < 416) {
            // l=2: cols [1024,1664), gate idx 256 + j/5
            const int j = (t - 256) * 4;
            const f32x4 v = __builtin_nontemporal_load((const f32x4*)(rin + 1024) + (t - 256));
            o.x = v.x * sg[256 + (j + 0) / 5];
            o.y = v.y * sg[256 + (j + 1) / 5];
            o.z = v.z * sg[256 + (j + 2) / 5];
            o.w = v.w * sg[256 + (j + 3) / 5];
        } else {
            // l=3: cols [1664,2112), gate idx 384 + j/7
            const int j = (t - 416) * 4;
            const f32x4 v = __builtin_nontemporal_load((const f32x4*)(rin + 1664) + (t - 416));
            o.x = v.x * sg[384 + (j + 0) / 7];
            o.y = v.y * sg[384 + (j + 1) / 7];
            o.z = v.z * sg[384 + (j + 2) / 7];
            o.w = v.w * sg[384 + (j + 3) / 7];
        }
        __builtin_nontemporal_store(o, (f32x4*)(rout + t * 4));
    }
}

extern "C" void kernel_launch(void* const* d_in, const int* in_sizes, int n_in,
                              void* d_out, int out_size, void* d_ws, size_t ws_size,
                              hipStream_t stream) {
    const float* in = (const float*)d_in[0];
    float* out = (float*)d_out;
    const int n_rows = in_sizes[0] / FEAT;   // 65536
    gated_kernel<<<n_rows, 256, 0, stream>>>(in, out);
}